// Round 6
// baseline (2597.133 us; speedup 1.0000x reference)
//
#include <hip/hip_runtime.h>

// ---------------------------------------------------------------------------
// TypeNet: 3 branches x (BN1 -> flattened LSTM (2048 steps) -> BN2 -> LSTM (2048 steps))
// H = 128, gates = 512. Round 6: recurrence moved OFF the matrix pipe onto
// v_dot2_f32_f16 (no 16x column waste: 128 dot2/lane vs 128 redundant MFMAs).
// 256 threads/block (1 wave/SIMD); lane pair (2j,2j+1) owns j's 4 gate rows
// (p=0: i,g; p=1: f,o); gate exchange = one in-wave ds_swizzle xor1; one
// lgkm-only barrier per step.
// ---------------------------------------------------------------------------

typedef _Float16 half2_t __attribute__((ext_vector_type(2)));
typedef _Float16 half4_t __attribute__((ext_vector_type(4)));
typedef _Float16 half8 __attribute__((ext_vector_type(8)));
typedef float float4_t __attribute__((ext_vector_type(4)));

__device__ __forceinline__ float fast_exp(float x) {
  return __builtin_amdgcn_exp2f(x * 1.44269504f);
}
__device__ __forceinline__ float fast_rcp(float x) { return __builtin_amdgcn_rcpf(x); }
__device__ __forceinline__ float sigm(float x) { return fast_rcp(1.0f + fast_exp(-x)); }
__device__ __forceinline__ float tanh_fast(float x) {
  return 1.0f - 2.0f * fast_rcp(1.0f + fast_exp(2.0f * x));
}

__device__ __forceinline__ float fdot2(half2_t a, half2_t b, float c) {
  return __builtin_amdgcn_fdot2(a, b, c, false);
}

// in-wave register exchange with lane^1 (pairs never cross the 32-lane group)
__device__ __forceinline__ float swz_xor1(float x) {
  return __int_as_float(__builtin_amdgcn_ds_swizzle(__float_as_int(x), 0x041F));
}

// LDS-visibility-only barrier: no vmcnt drain (global stores/loads in flight).
__device__ __forceinline__ void lds_barrier() {
  asm volatile("s_waitcnt lgkmcnt(0)\n\ts_barrier" ::: "memory");
}

// Gx half4 packing order: pos0=gate0(i), pos1=gate2(g), pos2=gate1(f), pos3=gate3(o)
// so lane p reads dword p = its two gates. pos = ((g&1)<<1)|(g>>1).

// ---------------------------------------------------------------------------
// K1: BN1 over branch slice [128,16,3]; writes xbn[br][s=t*128+b][d].
// ---------------------------------------------------------------------------
__global__ __launch_bounds__(128) void bn1_kernel(const float* __restrict__ x,
                                                  const float* __restrict__ g1,
                                                  const float* __restrict__ b1,
                                                  float* __restrict__ xbn) {
  const int br = blockIdx.x >> 4;
  const int t  = blockIdx.x & 15;
  const int b  = threadIdx.x;
  const float* px = x + (b * 48 + br * 16 + t) * 3;
  const float v0 = px[0], v1 = px[1], v2 = px[2];
  float s  = v0 + v1 + v2;
  float ss = v0 * v0 + v1 * v1 + v2 * v2;
  for (int off = 32; off; off >>= 1) {
    s  += __shfl_down(s, off);
    ss += __shfl_down(ss, off);
  }
  __shared__ float red[4];
  if ((threadIdx.x & 63) == 0) {
    red[(threadIdx.x >> 6) * 2]     = s;
    red[(threadIdx.x >> 6) * 2 + 1] = ss;
  }
  __syncthreads();
  const float S = red[0] + red[2], SS = red[1] + red[3];
  const float mean = S * (1.0f / 384.0f);
  const float var  = SS * (1.0f / 384.0f) - mean * mean;
  const float rstd = rsqrtf(var + 1e-5f);
  const float a  = g1[t] * rstd;
  const float sh = b1[t] - mean * a;
  float* dst = xbn + br * 6144 + (t * 128 + b) * 3;
  dst[0] = v0 * a + sh;
  dst[1] = v1 * a + sh;
  dst[2] = v2 * a + sh;
}

// ---------------------------------------------------------------------------
// K1b: G1x[br][s][j] packed f16x4 (order i,g,f,o) = Wih1 @ xbn[s] + biases.
// ---------------------------------------------------------------------------
__global__ __launch_bounds__(256) void g1x_kernel(const float* __restrict__ xbn,
                                                  const float* __restrict__ Wih1,
                                                  const float* __restrict__ bih1,
                                                  const float* __restrict__ bhh1,
                                                  half4_t* __restrict__ G1x) {
  const int br = blockIdx.x >> 10;
  const int sp = blockIdx.x & 1023;
  const int s  = sp * 2 + (threadIdx.x >> 7);
  const int j  = threadIdx.x & 127;
  const float* px = xbn + br * 6144 + s * 3;
  const float x0 = px[0], x1 = px[1], x2 = px[2];
  half4_t outv;
#pragma unroll
  for (int g = 0; g < 4; ++g) {
    const int row = g * 128 + j;
    const float a = bih1[row] + bhh1[row] + Wih1[row * 3] * x0 +
                    Wih1[row * 3 + 1] * x1 + Wih1[row * 3 + 2] * x2;
    outv[((g & 1) << 1) | (g >> 1)] = (_Float16)a;
  }
  G1x[(size_t)(br * 2048 + s) * 128 + j] = outv;
}

// ---------------------------------------------------------------------------
// K3a: BN2 stats per (branch, channel) over 2048 elems of H1.
// ---------------------------------------------------------------------------
__global__ __launch_bounds__(256) void bn2stats_kernel(const float* __restrict__ H1,
                                                       float* __restrict__ stats) {
  const int br = blockIdx.x >> 7;
  const int ch = blockIdx.x & 127;
  const float* base = H1 + (size_t)br * 262144 + ch * 128;
  float s = 0.f, ss = 0.f;
  for (int k = threadIdx.x; k < 2048; k += 256) {
    const int t1 = k >> 7, h = k & 127;
    const float v = base[t1 * 16384 + h];
    s += v;
    ss += v * v;
  }
  for (int off = 32; off; off >>= 1) {
    s  += __shfl_down(s, off);
    ss += __shfl_down(ss, off);
  }
  __shared__ float red[8];
  if ((threadIdx.x & 63) == 0) {
    red[(threadIdx.x >> 6) * 2]     = s;
    red[(threadIdx.x >> 6) * 2 + 1] = ss;
  }
  __syncthreads();
  if (threadIdx.x == 0) {
    const float S  = red[0] + red[2] + red[4] + red[6];
    const float SS = red[1] + red[3] + red[5] + red[7];
    const float mean = S * (1.0f / 2048.0f);
    const float var  = SS * (1.0f / 2048.0f) - mean * mean;
    stats[(br * 128 + ch) * 2]     = mean;
    stats[(br * 128 + ch) * 2 + 1] = rsqrtf(var + 1e-5f);
  }
}

// ---------------------------------------------------------------------------
// K3b: G2x (packed f16x4, order i,g,f,o) = Wih2 @ BN2(H1) + biases.
// ---------------------------------------------------------------------------
__global__ __launch_bounds__(256) void g2x_kernel(
    const float* __restrict__ H1, const float* __restrict__ stats,
    const float* __restrict__ g2, const float* __restrict__ b2v,
    const float* __restrict__ Wih2, const float* __restrict__ bih2,
    const float* __restrict__ bhh2, half4_t* __restrict__ G2x) {
  const int br = blockIdx.x >> 7;
  const int t2 = blockIdx.x & 127;
  __shared__ float xh[2048];
  __shared__ float wt[64 * 129];
  __shared__ half4_t res[2048];
  const float mean = stats[(br * 128 + t2) * 2];
  const float rstd = stats[(br * 128 + t2) * 2 + 1];
  const float a  = g2[t2] * rstd;
  const float sh = b2v[t2] - mean * a;
  for (int e = threadIdx.x; e < 2048; e += 256) {
    const int b2 = e >> 7, d = e & 127;
    xh[e] = H1[(size_t)br * 262144 + (size_t)(b2 * 128 + t2) * 128 + d] * a + sh;
  }
  const int gl  = threadIdx.x & 63;
  const int b2b = (threadIdx.x >> 6) * 4;
  for (int gt = 0; gt < 8; ++gt) {
    __syncthreads();
    for (int e = threadIdx.x; e < 8192; e += 256)
      wt[(e >> 7) * 129 + (e & 127)] = Wih2[gt * 8192 + e];
    __syncthreads();
    float a0 = 0.f, a1 = 0.f, a2 = 0.f, a3 = 0.f;
    for (int d = 0; d < 128; ++d) {
      const float w = wt[gl * 129 + d];
      a0 += w * xh[(b2b + 0) * 128 + d];
      a1 += w * xh[(b2b + 1) * 128 + d];
      a2 += w * xh[(b2b + 2) * 128 + d];
      a3 += w * xh[(b2b + 3) * 128 + d];
    }
    const int g    = gt * 64 + gl;
    const int gate = g >> 7;
    const int j    = g & 127;
    const int pos  = ((gate & 1) << 1) | (gate >> 1);
    const float bb = bih2[g] + bhh2[g];
    res[(b2b + 0) * 128 + j][pos] = (_Float16)(a0 + bb);
    res[(b2b + 1) * 128 + j][pos] = (_Float16)(a1 + bb);
    res[(b2b + 2) * 128 + j][pos] = (_Float16)(a2 + bb);
    res[(b2b + 3) * 128 + j][pos] = (_Float16)(a3 + bb);
  }
  __syncthreads();
  half4_t* dst = G2x + (size_t)(br * 2048 + t2 * 16) * 128;
  for (int e = threadIdx.x; e < 2048; e += 256) dst[e] = res[e];
}

// ---------------------------------------------------------------------------
// K2/K4: the recurrence on the VALU. 1 block/branch, 256 threads (4 waves,
// 1/SIMD). Lane 2j+p owns rows {p*128+j, (p+2)*128+j} as 128 half2 VGPRs.
// Per step: 16 broadcast ds_read_b128 of h; 128 v_dot2_f32_f16 into 8 accs;
// + packed Gx term; one ds_swizzle xor1 exchange; pairwise-redundant
// epilogue; p==0 writes h (LDS f16) and output. One lgkm-only barrier.
// ---------------------------------------------------------------------------
__global__ __launch_bounds__(256, 1) void lstm_kernel(
    const float* __restrict__ Whh, const float* __restrict__ h0s,
    const float* __restrict__ c0s, const half2_t* __restrict__ Gx,
    float* __restrict__ outp, int layer) {
  const int br  = blockIdx.x;
  const int tid = threadIdx.x;
  const int j   = tid >> 1;
  const int p   = tid & 1;

  __shared__ __align__(16) _Float16 h_sh[2][128];

  // stage W rows p*128+j (gate i or f) and (p+2)*128+j (gate g or o)
  half2_t wa[64], wb[64];
  {
    const float4_t* W4 = (const float4_t*)Whh;
    const int rA = p * 128 + j;
    const int rB = (p + 2) * 128 + j;
#pragma unroll
    for (int k = 0; k < 32; ++k) {
      const float4_t va = W4[rA * 32 + k];
      wa[2 * k]     = half2_t{(_Float16)va[0], (_Float16)va[1]};
      wa[2 * k + 1] = half2_t{(_Float16)va[2], (_Float16)va[3]};
      const float4_t vb = W4[rB * 32 + k];
      wb[2 * k]     = half2_t{(_Float16)vb[0], (_Float16)vb[1]};
      wb[2 * k + 1] = half2_t{(_Float16)vb[2], (_Float16)vb[3]};
    }
  }

  const int slot = 2 * br + layer;
  float c = c0s[slot * 128 + j];  // both pair lanes hold identical c
  if (tid < 128) h_sh[0][tid] = (_Float16)h0s[slot * 128 + tid];

  // packed gate-preact stream: lane reads dword p of [s][j] half4 (i,g | f,o)
  const half2_t* gb = Gx + (size_t)br * 2048 * 256 + j * 2 + p;
  half2_t cur = gb[0];
  half2_t nxt = gb[256];
  const half2_t* gpf = gb + 512;
  float* op = outp + (size_t)br * 262144 + j;

  __syncthreads();  // once; full drain fine

#pragma unroll 2
  for (int s = 0; s < 2048; ++s) {
    // broadcast-read h (all lanes same addresses -> LDS broadcast)
    const half8* hp = (const half8*)h_sh[s & 1];
    half8 h8[16];
#pragma unroll
    for (int i = 0; i < 16; ++i) h8[i] = hp[i];

    const half2_t pf = *gpf;   // prefetch s+2
    if (s < 2045) gpf += 256;  // clamp (re-reads last row; harmless)

    float a0 = 0.f, a1 = 0.f, a2 = 0.f, a3 = 0.f;
    float b0 = 0.f, b1 = 0.f, b2 = 0.f, b3 = 0.f;
#pragma unroll
    for (int i = 0; i < 16; ++i) {
      const half2_t* hh = (const half2_t*)&h8[i];
      a0 = fdot2(wa[4 * i + 0], hh[0], a0);
      a1 = fdot2(wa[4 * i + 1], hh[1], a1);
      a2 = fdot2(wa[4 * i + 2], hh[2], a2);
      a3 = fdot2(wa[4 * i + 3], hh[3], a3);
      b0 = fdot2(wb[4 * i + 0], hh[0], b0);
      b1 = fdot2(wb[4 * i + 1], hh[1], b1);
      b2 = fdot2(wb[4 * i + 2], hh[2], b2);
      b3 = fdot2(wb[4 * i + 3], hh[3], b3);
    }
    const float vA = ((a0 + a1) + (a2 + a3)) + (float)cur[0];  // gate i (p=0) / f (p=1)
    const float vB = ((b0 + b1) + (b2 + b3)) + (float)cur[1];  // gate g (p=0) / o (p=1)

    const float pA = swz_xor1(vA);  // partner's vA
    const float pB = swz_xor1(vB);  // partner's vB

    const float gi = p ? pA : vA;
    const float gf = p ? vA : pA;
    const float gg = p ? pB : vB;
    const float go = p ? vB : pB;

    const float iv = sigm(gi);
    const float fv = sigm(gf);
    const float gv = tanh_fast(gg);
    const float ov = sigm(go);
    c = fv * c + iv * gv;
    const float hv = ov * tanh_fast(c);

    if (p == 0) {
      h_sh[(s + 1) & 1][j] = (_Float16)hv;
      *op = hv;
    }
    op += 128;

    cur = nxt;
    nxt = pf;
    lds_barrier();  // h broadcast; lgkm-only, global ops stay in flight
  }
}

// ---------------------------------------------------------------------------
// Workspace layout (floats):
//   xbn   [3][2048][3]            @ 0        (18432)
//   H1    [3][2048][128]          @ 18432    (786432)
//   stats [3][128][2]             @ 804864   (768)
//   G1x   [3][2048][128] f16x4    @ 805632   (1572864 floats)
//   G2x   [3][2048][128] f16x4    @ 2378496  (1572864 floats)   total ~15.8 MB
// ---------------------------------------------------------------------------
extern "C" void kernel_launch(void* const* d_in, const int* in_sizes, int n_in,
                              void* d_out, int out_size, void* d_ws, size_t ws_size,
                              hipStream_t stream) {
  const float* x    = (const float*)d_in[0];
  const float* g1   = (const float*)d_in[1];
  const float* b1   = (const float*)d_in[2];
  const float* Wih1 = (const float*)d_in[3];
  const float* Whh1 = (const float*)d_in[4];
  const float* bih1 = (const float*)d_in[5];
  const float* bhh1 = (const float*)d_in[6];
  const float* g2   = (const float*)d_in[7];
  const float* b2   = (const float*)d_in[8];
  const float* Wih2 = (const float*)d_in[9];
  const float* Whh2 = (const float*)d_in[10];
  const float* bih2 = (const float*)d_in[11];
  const float* bhh2 = (const float*)d_in[12];
  const float* h0s  = (const float*)d_in[13];
  const float* c0s  = (const float*)d_in[14];

  float* ws   = (float*)d_ws;
  float* xbn  = ws;
  float* H1b  = ws + 18432;
  float* st   = ws + 18432 + 786432;
  half4_t* G1xb = (half4_t*)(ws + 805632);
  half4_t* G2xb = (half4_t*)(ws + 2378496);
  float* outp = (float*)d_out;

  bn1_kernel<<<48, 128, 0, stream>>>(x, g1, b1, xbn);
  g1x_kernel<<<3072, 256, 0, stream>>>(xbn, Wih1, bih1, bhh1, G1xb);
  lstm_kernel<<<3, 256, 0, stream>>>(Whh1, h0s, c0s, (const half2_t*)G1xb, H1b, 0);
  bn2stats_kernel<<<384, 256, 0, stream>>>(H1b, st);
  g2x_kernel<<<384, 256, 0, stream>>>(H1b, st, g2, b2, Wih2, bih2, bhh2, G2xb);
  lstm_kernel<<<3, 256, 0, stream>>>(Whh2, h0s, c0s, (const half2_t*)G2xb, outp, 1);
}

// Round 7
// 2548.154 us; speedup vs baseline: 1.0192x; 1.0192x over previous
//
#include <hip/hip_runtime.h>

// ---------------------------------------------------------------------------
// TypeNet: 3 branches x (BN1 -> flattened LSTM (2048 steps) -> BN2 -> LSTM (2048 steps))
// H = 128, gates = 512. Round 7: VALU fdot2 recurrence, k-split across quad
// lanes (lane g owns k-quarter [32g,32g+32) of ALL 4 gates of its j), gates
// recovered by xor1/xor2 butterfly (8 swizzles). Gx repacked into per-lane
// 16-step chunks -> 2 half8 loads / 16 steps, waited a whole chunk later
// (real prefetch, no per-step vmcnt stall). 512 thr (2 waves/SIMD). One
// lgkm-only barrier per step.
// ---------------------------------------------------------------------------

typedef _Float16 half2_t __attribute__((ext_vector_type(2)));
typedef _Float16 half4_t __attribute__((ext_vector_type(4)));
typedef _Float16 half8 __attribute__((ext_vector_type(8)));
typedef float float4_t __attribute__((ext_vector_type(4)));

__device__ __forceinline__ float fast_exp(float x) {
  return __builtin_amdgcn_exp2f(x * 1.44269504f);
}
__device__ __forceinline__ float fast_rcp(float x) { return __builtin_amdgcn_rcpf(x); }
__device__ __forceinline__ float sigm(float x) { return fast_rcp(1.0f + fast_exp(-x)); }
__device__ __forceinline__ float tanh_fast(float x) {
  return 1.0f - 2.0f * fast_rcp(1.0f + fast_exp(2.0f * x));
}

__device__ __forceinline__ float fdot2(half2_t a, half2_t b, float c) {
  return __builtin_amdgcn_fdot2(a, b, c, false);
}

// in-wave exchange: src lane = lane ^ mask (BitMode, and=0x1F)
__device__ __forceinline__ float swz_xor1(float x) {
  return __int_as_float(__builtin_amdgcn_ds_swizzle(__float_as_int(x), 0x041F));
}
__device__ __forceinline__ float swz_xor2(float x) {
  return __int_as_float(__builtin_amdgcn_ds_swizzle(__float_as_int(x), 0x081F));
}

// LDS-visibility-only barrier: no vmcnt drain (global stores/loads in flight).
__device__ __forceinline__ void lds_barrier() {
  asm volatile("s_waitcnt lgkmcnt(0)\n\ts_barrier" ::: "memory");
}

// Gx layout (halfs): ((br*128 + (s>>4))*512 + j*4 + g)*16 + (s&15)
// i.e. per (chunk, lane) a contiguous 16-step record of gate g's preact.

// ---------------------------------------------------------------------------
// K1: BN1 over branch slice [128,16,3]; writes xbn[br][s=t*128+b][d].
// ---------------------------------------------------------------------------
__global__ __launch_bounds__(128) void bn1_kernel(const float* __restrict__ x,
                                                  const float* __restrict__ g1,
                                                  const float* __restrict__ b1,
                                                  float* __restrict__ xbn) {
  const int br = blockIdx.x >> 4;
  const int t  = blockIdx.x & 15;
  const int b  = threadIdx.x;
  const float* px = x + (b * 48 + br * 16 + t) * 3;
  const float v0 = px[0], v1 = px[1], v2 = px[2];
  float s  = v0 + v1 + v2;
  float ss = v0 * v0 + v1 * v1 + v2 * v2;
  for (int off = 32; off; off >>= 1) {
    s  += __shfl_down(s, off);
    ss += __shfl_down(ss, off);
  }
  __shared__ float red[4];
  if ((threadIdx.x & 63) == 0) {
    red[(threadIdx.x >> 6) * 2]     = s;
    red[(threadIdx.x >> 6) * 2 + 1] = ss;
  }
  __syncthreads();
  const float S = red[0] + red[2], SS = red[1] + red[3];
  const float mean = S * (1.0f / 384.0f);
  const float var  = SS * (1.0f / 384.0f) - mean * mean;
  const float rstd = rsqrtf(var + 1e-5f);
  const float a  = g1[t] * rstd;
  const float sh = b1[t] - mean * a;
  float* dst = xbn + br * 6144 + (t * 128 + b) * 3;
  dst[0] = v0 * a + sh;
  dst[1] = v1 * a + sh;
  dst[2] = v2 * a + sh;
}

// ---------------------------------------------------------------------------
// K1b: G1x = Wih1 @ xbn + bih1 + bhh1, chunked layout (see above).
// thread = (s, j); writes 4 scattered f16.
// ---------------------------------------------------------------------------
__global__ __launch_bounds__(256) void g1x_kernel(const float* __restrict__ xbn,
                                                  const float* __restrict__ Wih1,
                                                  const float* __restrict__ bih1,
                                                  const float* __restrict__ bhh1,
                                                  _Float16* __restrict__ G1x) {
  const int br = blockIdx.x >> 10;
  const int sp = blockIdx.x & 1023;
  const int s  = sp * 2 + (threadIdx.x >> 7);
  const int j  = threadIdx.x & 127;
  const float* px = xbn + br * 6144 + s * 3;
  const float x0 = px[0], x1 = px[1], x2 = px[2];
  _Float16* base = G1x + ((size_t)(br * 128 + (s >> 4)) * 512 + j * 4) * 16 + (s & 15);
#pragma unroll
  for (int g = 0; g < 4; ++g) {
    const int row = g * 128 + j;
    const float a = bih1[row] + bhh1[row] + Wih1[row * 3] * x0 +
                    Wih1[row * 3 + 1] * x1 + Wih1[row * 3 + 2] * x2;
    base[g * 16] = (_Float16)a;
  }
}

// ---------------------------------------------------------------------------
// K3a: BN2 stats per (branch, channel) over 2048 elems of H1.
// ---------------------------------------------------------------------------
__global__ __launch_bounds__(256) void bn2stats_kernel(const float* __restrict__ H1,
                                                       float* __restrict__ stats) {
  const int br = blockIdx.x >> 7;
  const int ch = blockIdx.x & 127;
  const float* base = H1 + (size_t)br * 262144 + ch * 128;
  float s = 0.f, ss = 0.f;
  for (int k = threadIdx.x; k < 2048; k += 256) {
    const int t1 = k >> 7, h = k & 127;
    const float v = base[t1 * 16384 + h];
    s += v;
    ss += v * v;
  }
  for (int off = 32; off; off >>= 1) {
    s  += __shfl_down(s, off);
    ss += __shfl_down(ss, off);
  }
  __shared__ float red[8];
  if ((threadIdx.x & 63) == 0) {
    red[(threadIdx.x >> 6) * 2]     = s;
    red[(threadIdx.x >> 6) * 2 + 1] = ss;
  }
  __syncthreads();
  if (threadIdx.x == 0) {
    const float S  = red[0] + red[2] + red[4] + red[6];
    const float SS = red[1] + red[3] + red[5] + red[7];
    const float mean = S * (1.0f / 2048.0f);
    const float var  = SS * (1.0f / 2048.0f) - mean * mean;
    stats[(br * 128 + ch) * 2]     = mean;
    stats[(br * 128 + ch) * 2 + 1] = rsqrtf(var + 1e-5f);
  }
}

// ---------------------------------------------------------------------------
// K3b: G2x = Wih2 @ BN2(H1) + biases, chunked layout. Block (br, t2);
// s2 = t2*16 + b2 -> chunk == t2, pos == b2. half4 store per (row, 4 b2).
// ---------------------------------------------------------------------------
__global__ __launch_bounds__(256) void g2x_kernel(
    const float* __restrict__ H1, const float* __restrict__ stats,
    const float* __restrict__ g2, const float* __restrict__ b2v,
    const float* __restrict__ Wih2, const float* __restrict__ bih2,
    const float* __restrict__ bhh2, _Float16* __restrict__ G2x) {
  const int br = blockIdx.x >> 7;
  const int t2 = blockIdx.x & 127;
  __shared__ float xh[2048];
  __shared__ float wt[64 * 129];
  const float mean = stats[(br * 128 + t2) * 2];
  const float rstd = stats[(br * 128 + t2) * 2 + 1];
  const float a  = g2[t2] * rstd;
  const float sh = b2v[t2] - mean * a;
  for (int e = threadIdx.x; e < 2048; e += 256) {
    const int b2 = e >> 7, d = e & 127;
    xh[e] = H1[(size_t)br * 262144 + (size_t)(b2 * 128 + t2) * 128 + d] * a + sh;
  }
  const int gl  = threadIdx.x & 63;
  const int b2b = (threadIdx.x >> 6) * 4;
  for (int gt = 0; gt < 8; ++gt) {
    __syncthreads();
    for (int e = threadIdx.x; e < 8192; e += 256)
      wt[(e >> 7) * 129 + (e & 127)] = Wih2[gt * 8192 + e];
    __syncthreads();
    float a0 = 0.f, a1 = 0.f, a2 = 0.f, a3 = 0.f;
    for (int d = 0; d < 128; ++d) {
      const float w = wt[gl * 129 + d];
      a0 += w * xh[(b2b + 0) * 128 + d];
      a1 += w * xh[(b2b + 1) * 128 + d];
      a2 += w * xh[(b2b + 2) * 128 + d];
      a3 += w * xh[(b2b + 3) * 128 + d];
    }
    const int g    = gt * 64 + gl;
    const int gate = g >> 7;
    const int jj   = g & 127;
    const float bb = bih2[g] + bhh2[g];
    _Float16* dst = G2x + ((size_t)(br * 128 + t2) * 512 + jj * 4 + gate) * 16 + b2b;
    *reinterpret_cast<half4_t*>(dst) =
        half4_t{(_Float16)(a0 + bb), (_Float16)(a1 + bb),
                (_Float16)(a2 + bb), (_Float16)(a3 + bb)};
  }
}

// ---------------------------------------------------------------------------
// K2/K4: the recurrence. 1 block/branch, 512 threads (8 waves, 2/SIMD).
// Lane tid: j = tid>>2, g = tid&3. Owns k-quarter [32g,32g+32) of all 4
// gate rows of j (w[4][16] half2 = 64 VGPRs). Per step: 4 ds_read_b128 of h;
// 64 fdot2 (4 indep chains); acc[q] init = (g==q)? Gx preact : 0; butterfly
// xor1+xor2 -> full gates in every lane; redundant epilogue; g==0 writes.
// Gx: 2 half8 loads per 16-step chunk, waited one chunk later.
// ---------------------------------------------------------------------------
__global__ __launch_bounds__(512, 2) void lstm_kernel(
    const float* __restrict__ Whh, const float* __restrict__ h0s,
    const float* __restrict__ c0s, const _Float16* __restrict__ Gx,
    float* __restrict__ outp, int layer) {
  const int br  = blockIdx.x;
  const int tid = threadIdx.x;
  const int j   = tid >> 2;
  const int g   = tid & 3;

  __shared__ __align__(16) _Float16 h_sh[2][128];

  // ---- stage Whh: rows q*128+j, k in [32g, 32g+32), as f16 pairs ----
  half2_t w0[16], w1[16], w2[16], w3[16];
  {
    const float4_t* W4 = (const float4_t*)Whh;
#pragma unroll
    for (int k8 = 0; k8 < 8; ++k8) {
      const float4_t v0 = W4[((0 * 128 + j) * 128 + g * 32) / 4 + k8];
      w0[2 * k8]     = half2_t{(_Float16)v0[0], (_Float16)v0[1]};
      w0[2 * k8 + 1] = half2_t{(_Float16)v0[2], (_Float16)v0[3]};
      const float4_t v1 = W4[((1 * 128 + j) * 128 + g * 32) / 4 + k8];
      w1[2 * k8]     = half2_t{(_Float16)v1[0], (_Float16)v1[1]};
      w1[2 * k8 + 1] = half2_t{(_Float16)v1[2], (_Float16)v1[3]};
      const float4_t v2 = W4[((2 * 128 + j) * 128 + g * 32) / 4 + k8];
      w2[2 * k8]     = half2_t{(_Float16)v2[0], (_Float16)v2[1]};
      w2[2 * k8 + 1] = half2_t{(_Float16)v2[2], (_Float16)v2[3]};
      const float4_t v3 = W4[((3 * 128 + j) * 128 + g * 32) / 4 + k8];
      w3[2 * k8]     = half2_t{(_Float16)v3[0], (_Float16)v3[1]};
      w3[2 * k8 + 1] = half2_t{(_Float16)v3[2], (_Float16)v3[3]};
    }
  }

  const int slot = 2 * br + layer;
  float c = c0s[slot * 128 + j];  // quad lanes hold identical c
  if (tid < 128) h_sh[0][tid] = (_Float16)h0s[slot * 128 + tid];

  const bool gm0 = (g == 0), gm1 = (g == 1), gm2 = (g == 2), gm3 = (g == 3);

  // Gx chunk stream: record = 16 halfs at ((br*128+ch)*512 + tid)*16
  const half8* gq = (const half8*)Gx;
  size_t rec = ((size_t)(br * 128) * 512 + tid) * 2;  // in half8 units
  half8 curA = gq[rec], curB = gq[rec + 1];
  float* op = outp + (size_t)br * 262144 + j;

  __syncthreads();  // once; full drain fine

  for (int ch = 0; ch < 128; ++ch) {
    const int chn = (ch < 127) ? ch + 1 : 127;
    const size_t nrec = ((size_t)(br * 128 + chn) * 512 + tid) * 2;
    const half8 nA = gq[nrec], nB = gq[nrec + 1];  // waited at chunk end

#pragma unroll
    for (int u = 0; u < 16; ++u) {
      // h read: this lane's k-quarter
      const half8* hb = (const half8*)(&h_sh[u & 1][g * 32]);
      half8 hr0 = hb[0], hr1 = hb[1], hr2 = hb[2], hr3 = hb[3];

      const float pre = (float)((u < 8) ? curA[u] : curB[u - 8]);
      float a0 = gm0 ? pre : 0.f;
      float a1 = gm1 ? pre : 0.f;
      float a2 = gm2 ? pre : 0.f;
      float a3 = gm3 ? pre : 0.f;

      const half2_t* hh0 = (const half2_t*)&hr0;
      const half2_t* hh1 = (const half2_t*)&hr1;
      const half2_t* hh2 = (const half2_t*)&hr2;
      const half2_t* hh3 = (const half2_t*)&hr3;
#pragma unroll
      for (int k = 0; k < 4; ++k) {
        a0 = fdot2(w0[k], hh0[k], a0);
        a1 = fdot2(w1[k], hh0[k], a1);
        a2 = fdot2(w2[k], hh0[k], a2);
        a3 = fdot2(w3[k], hh0[k], a3);
        a0 = fdot2(w0[4 + k], hh1[k], a0);
        a1 = fdot2(w1[4 + k], hh1[k], a1);
        a2 = fdot2(w2[4 + k], hh1[k], a2);
        a3 = fdot2(w3[4 + k], hh1[k], a3);
        a0 = fdot2(w0[8 + k], hh2[k], a0);
        a1 = fdot2(w1[8 + k], hh2[k], a1);
        a2 = fdot2(w2[8 + k], hh2[k], a2);
        a3 = fdot2(w3[8 + k], hh2[k], a3);
        a0 = fdot2(w0[12 + k], hh3[k], a0);
        a1 = fdot2(w1[12 + k], hh3[k], a1);
        a2 = fdot2(w2[12 + k], hh3[k], a2);
        a3 = fdot2(w3[12 + k], hh3[k], a3);
      }

      // butterfly across the quad: after xor1+xor2 every lane has full sums
      a0 += swz_xor1(a0);
      a1 += swz_xor1(a1);
      a2 += swz_xor1(a2);
      a3 += swz_xor1(a3);
      a0 += swz_xor2(a0);
      a1 += swz_xor2(a1);
      a2 += swz_xor2(a2);
      a3 += swz_xor2(a3);

      const float iv = sigm(a0);
      const float fv = sigm(a1);
      const float gv = tanh_fast(a2);
      const float ov = sigm(a3);
      c = fv * c + iv * gv;
      const float hv = ov * tanh_fast(c);

      if (g == 0) {
        h_sh[(u + 1) & 1][j] = (_Float16)hv;
        *op = hv;
      }
      op += 128;
      lds_barrier();  // h broadcast; lgkm-only
    }

    curA = nA;  // vmcnt wait lands here, one full chunk after issue
    curB = nB;
  }
}

// ---------------------------------------------------------------------------
// Workspace layout (floats):
//   xbn   [3][2048][3]            @ 0        (18432)
//   H1    [3][2048][128]          @ 18432    (786432)
//   stats [3][128][2]             @ 804864   (768)
//   G1x   chunked f16             @ 805632   (1572864 floats)
//   G2x   chunked f16             @ 2378496  (1572864 floats)   total ~15.8 MB
// ---------------------------------------------------------------------------
extern "C" void kernel_launch(void* const* d_in, const int* in_sizes, int n_in,
                              void* d_out, int out_size, void* d_ws, size_t ws_size,
                              hipStream_t stream) {
  const float* x    = (const float*)d_in[0];
  const float* g1   = (const float*)d_in[1];
  const float* b1   = (const float*)d_in[2];
  const float* Wih1 = (const float*)d_in[3];
  const float* Whh1 = (const float*)d_in[4];
  const float* bih1 = (const float*)d_in[5];
  const float* bhh1 = (const float*)d_in[6];
  const float* g2   = (const float*)d_in[7];
  const float* b2   = (const float*)d_in[8];
  const float* Wih2 = (const float*)d_in[9];
  const float* Whh2 = (const float*)d_in[10];
  const float* bih2 = (const float*)d_in[11];
  const float* bhh2 = (const float*)d_in[12];
  const float* h0s  = (const float*)d_in[13];
  const float* c0s  = (const float*)d_in[14];

  float* ws   = (float*)d_ws;
  float* xbn  = ws;
  float* H1b  = ws + 18432;
  float* st   = ws + 18432 + 786432;
  _Float16* G1xb = (_Float16*)(ws + 805632);
  _Float16* G2xb = (_Float16*)(ws + 2378496);
  float* outp = (float*)d_out;

  bn1_kernel<<<48, 128, 0, stream>>>(x, g1, b1, xbn);
  g1x_kernel<<<3072, 256, 0, stream>>>(xbn, Wih1, bih1, bhh1, G1xb);
  lstm_kernel<<<3, 512, 0, stream>>>(Whh1, h0s, c0s, G1xb, H1b, 0);
  bn2stats_kernel<<<384, 256, 0, stream>>>(H1b, st);
  g2x_kernel<<<384, 256, 0, stream>>>(H1b, st, g2, b2, Wih2, bih2, bhh2, G2xb);
  lstm_kernel<<<3, 512, 0, stream>>>(Whh2, h0s, c0s, G2xb, outp, 1);
}

// Round 8
// 2164.724 us; speedup vs baseline: 1.1998x; 1.1771x over previous
//
#include <hip/hip_runtime.h>

// ---------------------------------------------------------------------------
// TypeNet: 3 branches x (BN1 -> flattened LSTM (2048 steps) -> BN2 -> LSTM (2048 steps))
// H = 128, gates = 512. Round 8: R7's fdot2 recurrence with (1) quad butterfly
// moved from ds_swizzle (LDS pipe, ~2x120cyc serial) to DPP quad_perm adds
// (pure VALU), and (2) gate preacts pre-scaled by log2e at staging so the
// epilogue feeds v_exp directly. One lgkm-only barrier per step remains.
// ---------------------------------------------------------------------------

typedef _Float16 half2_t __attribute__((ext_vector_type(2)));
typedef _Float16 half4_t __attribute__((ext_vector_type(4)));
typedef _Float16 half8 __attribute__((ext_vector_type(8)));
typedef float float4_t __attribute__((ext_vector_type(4)));

#define LOG2E 1.44269504f

__device__ __forceinline__ float fast_rcp(float x) { return __builtin_amdgcn_rcpf(x); }
__device__ __forceinline__ float exp2b(float x) { return __builtin_amdgcn_exp2f(x); }

__device__ __forceinline__ float fdot2(half2_t a, half2_t b, float c) {
  return __builtin_amdgcn_fdot2(a, b, c, false);
}

// quad butterfly on the VALU: DPP quad_perm, no LDS pipe.
// xor1: [1,0,3,2] -> 0xB1 ; xor2: [2,3,0,1] -> 0x4E
__device__ __forceinline__ float qadd_xor1(float x) {
  return x + __int_as_float(__builtin_amdgcn_update_dpp(
                 0, __float_as_int(x), 0xB1, 0xF, 0xF, true));
}
__device__ __forceinline__ float qadd_xor2(float x) {
  return x + __int_as_float(__builtin_amdgcn_update_dpp(
                 0, __float_as_int(x), 0x4E, 0xF, 0xF, true));
}

// LDS-visibility-only barrier: no vmcnt drain (global stores/loads in flight).
__device__ __forceinline__ void lds_barrier() {
  asm volatile("s_waitcnt lgkmcnt(0)\n\ts_barrier" ::: "memory");
}

// Gx layout (halfs): ((br*128 + (s>>4))*512 + j*4 + g)*16 + (s&15)
// per (chunk, lane): contiguous 16-step record of gate g's preact, PRE-SCALED
// by log2e.

// ---------------------------------------------------------------------------
// K1: BN1 over branch slice [128,16,3]; writes xbn[br][s=t*128+b][d].
// ---------------------------------------------------------------------------
__global__ __launch_bounds__(128) void bn1_kernel(const float* __restrict__ x,
                                                  const float* __restrict__ g1,
                                                  const float* __restrict__ b1,
                                                  float* __restrict__ xbn) {
  const int br = blockIdx.x >> 4;
  const int t  = blockIdx.x & 15;
  const int b  = threadIdx.x;
  const float* px = x + (b * 48 + br * 16 + t) * 3;
  const float v0 = px[0], v1 = px[1], v2 = px[2];
  float s  = v0 + v1 + v2;
  float ss = v0 * v0 + v1 * v1 + v2 * v2;
  for (int off = 32; off; off >>= 1) {
    s  += __shfl_down(s, off);
    ss += __shfl_down(ss, off);
  }
  __shared__ float red[4];
  if ((threadIdx.x & 63) == 0) {
    red[(threadIdx.x >> 6) * 2]     = s;
    red[(threadIdx.x >> 6) * 2 + 1] = ss;
  }
  __syncthreads();
  const float S = red[0] + red[2], SS = red[1] + red[3];
  const float mean = S * (1.0f / 384.0f);
  const float var  = SS * (1.0f / 384.0f) - mean * mean;
  const float rstd = rsqrtf(var + 1e-5f);
  const float a  = g1[t] * rstd;
  const float sh = b1[t] - mean * a;
  float* dst = xbn + br * 6144 + (t * 128 + b) * 3;
  dst[0] = v0 * a + sh;
  dst[1] = v1 * a + sh;
  dst[2] = v2 * a + sh;
}

// ---------------------------------------------------------------------------
// K1b: G1x = (Wih1 @ xbn + bih1 + bhh1) * log2e, chunked layout.
// ---------------------------------------------------------------------------
__global__ __launch_bounds__(256) void g1x_kernel(const float* __restrict__ xbn,
                                                  const float* __restrict__ Wih1,
                                                  const float* __restrict__ bih1,
                                                  const float* __restrict__ bhh1,
                                                  _Float16* __restrict__ G1x) {
  const int br = blockIdx.x >> 10;
  const int sp = blockIdx.x & 1023;
  const int s  = sp * 2 + (threadIdx.x >> 7);
  const int j  = threadIdx.x & 127;
  const float* px = xbn + br * 6144 + s * 3;
  const float x0 = px[0], x1 = px[1], x2 = px[2];
  _Float16* base = G1x + ((size_t)(br * 128 + (s >> 4)) * 512 + j * 4) * 16 + (s & 15);
#pragma unroll
  for (int g = 0; g < 4; ++g) {
    const int row = g * 128 + j;
    const float a = bih1[row] + bhh1[row] + Wih1[row * 3] * x0 +
                    Wih1[row * 3 + 1] * x1 + Wih1[row * 3 + 2] * x2;
    base[g * 16] = (_Float16)(a * LOG2E);
  }
}

// ---------------------------------------------------------------------------
// K3a: BN2 stats per (branch, channel) over 2048 elems of H1.
// ---------------------------------------------------------------------------
__global__ __launch_bounds__(256) void bn2stats_kernel(const float* __restrict__ H1,
                                                       float* __restrict__ stats) {
  const int br = blockIdx.x >> 7;
  const int ch = blockIdx.x & 127;
  const float* base = H1 + (size_t)br * 262144 + ch * 128;
  float s = 0.f, ss = 0.f;
  for (int k = threadIdx.x; k < 2048; k += 256) {
    const int t1 = k >> 7, h = k & 127;
    const float v = base[t1 * 16384 + h];
    s += v;
    ss += v * v;
  }
  for (int off = 32; off; off >>= 1) {
    s  += __shfl_down(s, off);
    ss += __shfl_down(ss, off);
  }
  __shared__ float red[8];
  if ((threadIdx.x & 63) == 0) {
    red[(threadIdx.x >> 6) * 2]     = s;
    red[(threadIdx.x >> 6) * 2 + 1] = ss;
  }
  __syncthreads();
  if (threadIdx.x == 0) {
    const float S  = red[0] + red[2] + red[4] + red[6];
    const float SS = red[1] + red[3] + red[5] + red[7];
    const float mean = S * (1.0f / 2048.0f);
    const float var  = SS * (1.0f / 2048.0f) - mean * mean;
    stats[(br * 128 + ch) * 2]     = mean;
    stats[(br * 128 + ch) * 2 + 1] = rsqrtf(var + 1e-5f);
  }
}

// ---------------------------------------------------------------------------
// K3b: G2x = (Wih2 @ BN2(H1) + biases) * log2e, chunked layout.
// ---------------------------------------------------------------------------
__global__ __launch_bounds__(256) void g2x_kernel(
    const float* __restrict__ H1, const float* __restrict__ stats,
    const float* __restrict__ g2, const float* __restrict__ b2v,
    const float* __restrict__ Wih2, const float* __restrict__ bih2,
    const float* __restrict__ bhh2, _Float16* __restrict__ G2x) {
  const int br = blockIdx.x >> 7;
  const int t2 = blockIdx.x & 127;
  __shared__ float xh[2048];
  __shared__ float wt[64 * 129];
  const float mean = stats[(br * 128 + t2) * 2];
  const float rstd = stats[(br * 128 + t2) * 2 + 1];
  const float a  = g2[t2] * rstd;
  const float sh = b2v[t2] - mean * a;
  for (int e = threadIdx.x; e < 2048; e += 256) {
    const int b2 = e >> 7, d = e & 127;
    xh[e] = H1[(size_t)br * 262144 + (size_t)(b2 * 128 + t2) * 128 + d] * a + sh;
  }
  const int gl  = threadIdx.x & 63;
  const int b2b = (threadIdx.x >> 6) * 4;
  for (int gt = 0; gt < 8; ++gt) {
    __syncthreads();
    for (int e = threadIdx.x; e < 8192; e += 256)
      wt[(e >> 7) * 129 + (e & 127)] = Wih2[gt * 8192 + e];
    __syncthreads();
    float a0 = 0.f, a1 = 0.f, a2 = 0.f, a3 = 0.f;
    for (int d = 0; d < 128; ++d) {
      const float w = wt[gl * 129 + d];
      a0 += w * xh[(b2b + 0) * 128 + d];
      a1 += w * xh[(b2b + 1) * 128 + d];
      a2 += w * xh[(b2b + 2) * 128 + d];
      a3 += w * xh[(b2b + 3) * 128 + d];
    }
    const int g    = gt * 64 + gl;
    const int gate = g >> 7;
    const int jj   = g & 127;
    const float bb = bih2[g] + bhh2[g];
    _Float16* dst = G2x + ((size_t)(br * 128 + t2) * 512 + jj * 4 + gate) * 16 + b2b;
    *reinterpret_cast<half4_t*>(dst) =
        half4_t{(_Float16)((a0 + bb) * LOG2E), (_Float16)((a1 + bb) * LOG2E),
                (_Float16)((a2 + bb) * LOG2E), (_Float16)((a3 + bb) * LOG2E)};
  }
}

// ---------------------------------------------------------------------------
// K2/K4: the recurrence. 1 block/branch, 512 threads (8 waves, 2/SIMD).
// Lane tid: j = tid>>2, g = tid&3. Owns k-quarter [32g,32g+32) of all 4
// gate rows of j, weights pre-scaled by log2e (64 half2 VGPRs). Per step:
// 4 ds_read_b128 of h; 64 fdot2 (4 indep chains); acc[q] init = (g==q)?
// preact : 0; DPP quad butterfly (xor1+xor2, pure VALU); redundant epilogue
// (exp2-direct); g==0 writes h + output. One lgkm-only barrier per step.
// Gx: 2 half8 loads per 16-step chunk, waited one chunk later.
// ---------------------------------------------------------------------------
__global__ __launch_bounds__(512, 2) void lstm_kernel(
    const float* __restrict__ Whh, const float* __restrict__ h0s,
    const float* __restrict__ c0s, const _Float16* __restrict__ Gx,
    float* __restrict__ outp, int layer) {
  const int br  = blockIdx.x;
  const int tid = threadIdx.x;
  const int j   = tid >> 2;
  const int g   = tid & 3;

  __shared__ __align__(16) _Float16 h_sh[2][128];

  // ---- stage Whh rows q*128+j, k in [32g,32g+32), f16, pre-scaled log2e ----
  half2_t w0[16], w1[16], w2[16], w3[16];
  {
    const float4_t* W4 = (const float4_t*)Whh;
#pragma unroll
    for (int k8 = 0; k8 < 8; ++k8) {
      const float4_t v0 = W4[((0 * 128 + j) * 128 + g * 32) / 4 + k8];
      w0[2 * k8]     = half2_t{(_Float16)(v0[0] * LOG2E), (_Float16)(v0[1] * LOG2E)};
      w0[2 * k8 + 1] = half2_t{(_Float16)(v0[2] * LOG2E), (_Float16)(v0[3] * LOG2E)};
      const float4_t v1 = W4[((1 * 128 + j) * 128 + g * 32) / 4 + k8];
      w1[2 * k8]     = half2_t{(_Float16)(v1[0] * LOG2E), (_Float16)(v1[1] * LOG2E)};
      w1[2 * k8 + 1] = half2_t{(_Float16)(v1[2] * LOG2E), (_Float16)(v1[3] * LOG2E)};
      const float4_t v2 = W4[((2 * 128 + j) * 128 + g * 32) / 4 + k8];
      w2[2 * k8]     = half2_t{(_Float16)(v2[0] * LOG2E), (_Float16)(v2[1] * LOG2E)};
      w2[2 * k8 + 1] = half2_t{(_Float16)(v2[2] * LOG2E), (_Float16)(v2[3] * LOG2E)};
      const float4_t v3 = W4[((3 * 128 + j) * 128 + g * 32) / 4 + k8];
      w3[2 * k8]     = half2_t{(_Float16)(v3[0] * LOG2E), (_Float16)(v3[1] * LOG2E)};
      w3[2 * k8 + 1] = half2_t{(_Float16)(v3[2] * LOG2E), (_Float16)(v3[3] * LOG2E)};
    }
  }

  const int slot = 2 * br + layer;
  float c = c0s[slot * 128 + j];  // quad lanes hold identical c
  if (tid < 128) h_sh[0][tid] = (_Float16)h0s[slot * 128 + tid];

  const bool gm0 = (g == 0), gm1 = (g == 1), gm2 = (g == 2), gm3 = (g == 3);

  // Gx chunk stream: record = 16 halfs at ((br*128+ch)*512 + tid)*16
  const half8* gq = (const half8*)Gx;
  size_t rec = ((size_t)(br * 128) * 512 + tid) * 2;  // in half8 units
  half8 curA = gq[rec], curB = gq[rec + 1];
  float* op = outp + (size_t)br * 262144 + j;

  __syncthreads();  // once; full drain fine

  for (int chk = 0; chk < 128; ++chk) {
    const int chn = (chk < 127) ? chk + 1 : 127;
    const size_t nrec = ((size_t)(br * 128 + chn) * 512 + tid) * 2;
    const half8 nA = gq[nrec], nB = gq[nrec + 1];  // waited at chunk end

#pragma unroll
    for (int u = 0; u < 16; ++u) {
      // h read: this lane's k-quarter
      const half8* hb = (const half8*)(&h_sh[u & 1][g * 32]);
      half8 hr0 = hb[0], hr1 = hb[1], hr2 = hb[2], hr3 = hb[3];

      const float pre = (float)((u < 8) ? curA[u] : curB[u - 8]);
      float a0 = gm0 ? pre : 0.f;
      float a1 = gm1 ? pre : 0.f;
      float a2 = gm2 ? pre : 0.f;
      float a3 = gm3 ? pre : 0.f;

      const half2_t* hh0 = (const half2_t*)&hr0;
      const half2_t* hh1 = (const half2_t*)&hr1;
      const half2_t* hh2 = (const half2_t*)&hr2;
      const half2_t* hh3 = (const half2_t*)&hr3;
#pragma unroll
      for (int k = 0; k < 4; ++k) {
        a0 = fdot2(w0[k], hh0[k], a0);
        a1 = fdot2(w1[k], hh0[k], a1);
        a2 = fdot2(w2[k], hh0[k], a2);
        a3 = fdot2(w3[k], hh0[k], a3);
        a0 = fdot2(w0[4 + k], hh1[k], a0);
        a1 = fdot2(w1[4 + k], hh1[k], a1);
        a2 = fdot2(w2[4 + k], hh1[k], a2);
        a3 = fdot2(w3[4 + k], hh1[k], a3);
        a0 = fdot2(w0[8 + k], hh2[k], a0);
        a1 = fdot2(w1[8 + k], hh2[k], a1);
        a2 = fdot2(w2[8 + k], hh2[k], a2);
        a3 = fdot2(w3[8 + k], hh2[k], a3);
        a0 = fdot2(w0[12 + k], hh3[k], a0);
        a1 = fdot2(w1[12 + k], hh3[k], a1);
        a2 = fdot2(w2[12 + k], hh3[k], a2);
        a3 = fdot2(w3[12 + k], hh3[k], a3);
      }

      // quad butterfly on the VALU (DPP): full gate sums in every lane
      a0 = qadd_xor1(a0);
      a1 = qadd_xor1(a1);
      a2 = qadd_xor1(a2);
      a3 = qadd_xor1(a3);
      a0 = qadd_xor2(a0);
      a1 = qadd_xor2(a1);
      a2 = qadd_xor2(a2);
      a3 = qadd_xor2(a3);

      // a* are log2e-scaled preacts: feed exp2 directly
      const float iv = fast_rcp(1.0f + exp2b(-a0));
      const float fv = fast_rcp(1.0f + exp2b(-a1));
      const float gv = 1.0f - 2.0f * fast_rcp(1.0f + exp2b(a2 + a2));
      const float ov = fast_rcp(1.0f + exp2b(-a3));
      c = fv * c + iv * gv;
      const float t  = 1.0f - 2.0f * fast_rcp(1.0f + exp2b(c * 2.88539008f));
      const float hv = ov * t;

      if (g == 0) {
        h_sh[(u + 1) & 1][j] = (_Float16)hv;
        *op = hv;
      }
      op += 128;
      lds_barrier();  // h broadcast; lgkm-only
    }

    curA = nA;  // vmcnt wait lands here, one full chunk after issue
    curB = nB;
  }
}

// ---------------------------------------------------------------------------
// Workspace layout (floats):
//   xbn   [3][2048][3]            @ 0        (18432)
//   H1    [3][2048][128]          @ 18432    (786432)
//   stats [3][128][2]             @ 804864   (768)
//   G1x   chunked f16             @ 805632   (1572864 floats)
//   G2x   chunked f16             @ 2378496  (1572864 floats)   total ~15.8 MB
// ---------------------------------------------------------------------------
extern "C" void kernel_launch(void* const* d_in, const int* in_sizes, int n_in,
                              void* d_out, int out_size, void* d_ws, size_t ws_size,
                              hipStream_t stream) {
  const float* x    = (const float*)d_in[0];
  const float* g1   = (const float*)d_in[1];
  const float* b1   = (const float*)d_in[2];
  const float* Wih1 = (const float*)d_in[3];
  const float* Whh1 = (const float*)d_in[4];
  const float* bih1 = (const float*)d_in[5];
  const float* bhh1 = (const float*)d_in[6];
  const float* g2   = (const float*)d_in[7];
  const float* b2   = (const float*)d_in[8];
  const float* Wih2 = (const float*)d_in[9];
  const float* Whh2 = (const float*)d_in[10];
  const float* bih2 = (const float*)d_in[11];
  const float* bhh2 = (const float*)d_in[12];
  const float* h0s  = (const float*)d_in[13];
  const float* c0s  = (const float*)d_in[14];

  float* ws   = (float*)d_ws;
  float* xbn  = ws;
  float* H1b  = ws + 18432;
  float* st   = ws + 18432 + 786432;
  _Float16* G1xb = (_Float16*)(ws + 805632);
  _Float16* G2xb = (_Float16*)(ws + 2378496);
  float* outp = (float*)d_out;

  bn1_kernel<<<48, 128, 0, stream>>>(x, g1, b1, xbn);
  g1x_kernel<<<3072, 256, 0, stream>>>(xbn, Wih1, bih1, bhh1, G1xb);
  lstm_kernel<<<3, 512, 0, stream>>>(Whh1, h0s, c0s, G1xb, H1b, 0);
  bn2stats_kernel<<<384, 256, 0, stream>>>(H1b, st);
  g2x_kernel<<<384, 256, 0, stream>>>(H1b, st, g2, b2, Wih2, bih2, bhh2, G2xb);
  lstm_kernel<<<3, 512, 0, stream>>>(Whh2, h0s, c0s, G2xb, outp, 1);
}